// Round 15
// baseline (580.948 us; speedup 1.0000x reference)
//
#include <hip/hip_runtime.h>

// Problem constants (fixed-shape: B=8192, IN=1024, N=4096, K=409)
#define BATCH 8192
#define INF   1024
#define NF    4096
#define BN_EPS 1e-5
#define NT    32     // K tiles of 32 (all 6 plane-products per tile)

typedef __attribute__((ext_vector_type(8))) short short8v;
typedef __attribute__((ext_vector_type(4))) float f32x4;

#define FENCE asm volatile("" ::: "memory")
#define BARRIER do { FENCE; __builtin_amdgcn_s_barrier(); FENCE; } while (0)

// ---------------------------------------------------------------------------
// Exact 3-way bf16 truncation split: x == bf16(h0)+bf16(h1)+bf16(h2) EXACTLY.
// ---------------------------------------------------------------------------
__device__ __forceinline__ void split3(float x, ushort& h0, ushort& h1, ushort& h2) {
    const unsigned u0 = __float_as_uint(x) & 0xFFFF0000u;
    const float    r1 = x - __uint_as_float(u0);
    const unsigned u1 = __float_as_uint(r1) & 0xFFFF0000u;
    const float    r2 = r1 - __uint_as_float(u1);
    h0 = (ushort)(u0 >> 16);
    h1 = (ushort)(u1 >> 16);
    h2 = (ushort)(__float_as_uint(r2) >> 16);
}

// ---------------------------------------------------------------------------
// Kernel 1 (fast path): merged prep — zero stats (block 0) + pre-split X
// (blocks [0,4096)) and masked W (blocks [4096,6144)) into 3 bf16 planes.
// ---------------------------------------------------------------------------
__global__ __launch_bounds__(256) void prep_kernel(
    const float* __restrict__ X, const float* __restrict__ W,
    const int* __restrict__ Mk,
    ushort* __restrict__ xs, ushort* __restrict__ wsp,
    double* __restrict__ dz)
{
    const int blk = blockIdx.x;
    const int t   = threadIdx.x;
    if (blk == 0) {
#pragma unroll
        for (int i = 0; i < 32; ++i) dz[i * 256 + t] = 0.0;   // 2*NF doubles
    }
    if (blk < 4096) {
        const size_t base = ((size_t)blk * 256 + t) * 8;
        const size_t LS = (size_t)BATCH * INF;
        const float4 v0 = *(const float4*)(X + base);
        const float4 v1 = *(const float4*)(X + base + 4);
        const float v[8] = {v0.x, v0.y, v0.z, v0.w, v1.x, v1.y, v1.z, v1.w};
        short8v s0, s1, s2;
#pragma unroll
        for (int i = 0; i < 8; ++i) {
            ushort h0, h1, h2;
            split3(v[i], h0, h1, h2);
            s0[i] = (short)h0; s1[i] = (short)h1; s2[i] = (short)h2;
        }
        *(short8v*)&xs[base]          = s0;
        *(short8v*)&xs[base + LS]     = s1;
        *(short8v*)&xs[base + 2 * LS] = s2;
    } else {
        const size_t base = ((size_t)(blk - 4096) * 256 + t) * 8;
        const size_t LS = (size_t)NF * INF;
        const float4 v0 = *(const float4*)(W + base);
        const float4 v1 = *(const float4*)(W + base + 4);
        const int4   m0 = *(const int4*)(Mk + base);
        const int4   m1 = *(const int4*)(Mk + base + 4);
        const float v[8] = {v0.x * (float)m0.x, v0.y * (float)m0.y,
                            v0.z * (float)m0.z, v0.w * (float)m0.w,
                            v1.x * (float)m1.x, v1.y * (float)m1.y,
                            v1.z * (float)m1.z, v1.w * (float)m1.w};
        short8v s0, s1, s2;
#pragma unroll
        for (int i = 0; i < 8; ++i) {
            ushort h0, h1, h2;
            split3(v[i], h0, h1, h2);
            s0[i] = (short)h0; s1[i] = (short)h1; s2[i] = (short)h2;
        }
        *(short8v*)&wsp[base]          = s0;
        *(short8v*)&wsp[base + LS]     = s1;
        *(short8v*)&wsp[base + 2 * LS] = s2;
    }
}

// ---------------------------------------------------------------------------
// Kernel 1 (fallback): zero the f64 stats accumulators
// ---------------------------------------------------------------------------
__global__ void zero_ws(double* __restrict__ p) {
    p[blockIdx.x * 256 + threadIdx.x] = 0.0;
}

// ---------------------------------------------------------------------------
// direct global->LDS 16B staging
// ---------------------------------------------------------------------------
__device__ __forceinline__ void gload16(const ushort* g, ushort* l) {
    __builtin_amdgcn_global_load_lds(
        (const __attribute__((address_space(1))) void*)g,
        (__attribute__((address_space(3))) void*)l, 16, 0, 0);
}

// ---------------------------------------------------------------------------
// Kernel 2 (fast path): R12-R14's proven GEMM (MfmaUtil ~49%, 0 conflicts)
// + fused column-stats epilogue. FROZEN.
// ---------------------------------------------------------------------------
__global__ __launch_bounds__(512) void gemm_mfma_fuse(
    const ushort* __restrict__ Xs, const ushort* __restrict__ Wsp,
    const float* __restrict__ bias, float* __restrict__ Y,
    double* __restrict__ dsum, double* __restrict__ dsqs)
{
    extern __shared__ ushort sm[];   // 3 bufs x 6 planes x 4096 ushorts = 144KB
    const size_t LSX = (size_t)BATCH * INF;
    const size_t LSW = (size_t)NF * INF;

    const int t    = threadIdx.x;
    const int row0 = blockIdx.y * 128;
    const int col0 = blockIdx.x * 128;

    const int l   = t & 63;
    const int l15 = l & 15;
    const int hi  = l >> 4;
    const int wid = t >> 6;
    const int wm  = wid >> 1;        // 0..3 -> M offset wm*32
    const int wn  = wid & 1;         // 0..1 -> N offset wn*64

    const int srow  = t >> 2;                      // 0..127
    const int sunit = (t & 3) ^ ((t >> 3) & 3);    // swizzled source 16B-unit
    const int uoff = (hi ^ ((l15 >> 1) & 3)) << 3; // swizzled ds_read unit

    f32x4  acc[2][4];
    double mst[2][4][4];
#pragma unroll
    for (int mf = 0; mf < 2; ++mf)
#pragma unroll
        for (int nf = 0; nf < 4; ++nf) {
            acc[mf][nf] = (f32x4){0.f, 0.f, 0.f, 0.f};
#pragma unroll
            for (int r = 0; r < 4; ++r) mst[mf][nf][r] = 0.0;
        }

#define PB(b, p) (sm + (b) * 24576 + (p) * 4096)

#pragma unroll
    for (int tt = 0; tt < 2; ++tt) {
#pragma unroll
        for (int p = 0; p < 3; ++p)
            gload16(Xs + (size_t)p * LSX + (size_t)(row0 + srow) * INF + tt * 32 + sunit * 8,
                    PB(tt, p) + (size_t)t * 8);
#pragma unroll
        for (int p = 0; p < 3; ++p)
            gload16(Wsp + (size_t)p * LSW + (size_t)(col0 + srow) * INF + tt * 32 + sunit * 8,
                    PB(tt, 3 + p) + (size_t)t * 8);
    }
    asm volatile("s_waitcnt vmcnt(6)" ::: "memory");
    BARRIER;

#define TILE(tt, CUR, DST) do {                                               \
    if ((tt) + 2 < NT) {                                                      \
        const int kof_ = ((tt) + 2) * 32;                                     \
        _Pragma("unroll")                                                     \
        for (int p = 0; p < 3; ++p)                                           \
            gload16(Xs + (size_t)p * LSX + (size_t)(row0 + srow) * INF + kof_ + sunit * 8, \
                    PB(DST, p) + (size_t)t * 8);                              \
        _Pragma("unroll")                                                     \
        for (int p = 0; p < 3; ++p)                                           \
            gload16(Wsp + (size_t)p * LSW + (size_t)(col0 + srow) * INF + kof_ + sunit * 8, \
                    PB(DST, 3 + p) + (size_t)t * 8);                          \
    }                                                                         \
    short8v A_[2][3], B_[4][3];                                               \
    _Pragma("unroll")                                                         \
    for (int mf = 0; mf < 2; ++mf) {                                          \
        const int ra = (wm * 32 + mf * 16 + l15) * 32 + uoff;                 \
        _Pragma("unroll")                                                     \
        for (int p = 0; p < 3; ++p)                                           \
            A_[mf][p] = *(const short8v*)&PB(CUR, p)[ra];                     \
    }                                                                         \
    _Pragma("unroll")                                                         \
    for (int nf = 0; nf < 4; ++nf) {                                          \
        const int rb = (wn * 64 + nf * 16 + l15) * 32 + uoff;                 \
        _Pragma("unroll")                                                     \
        for (int p = 0; p < 3; ++p)                                           \
            B_[nf][p] = *(const short8v*)&PB(CUR, 3 + p)[rb];                 \
    }                                                                         \
    __builtin_amdgcn_s_setprio(1);                                            \
    _Pragma("unroll")                                                         \
    for (int mf = 0; mf < 2; ++mf)                                            \
        _Pragma("unroll")                                                     \
        for (int nf = 0; nf < 4; ++nf) {                                      \
            f32x4 c = acc[mf][nf];                                            \
            c = __builtin_amdgcn_mfma_f32_16x16x32_bf16(A_[mf][0], B_[nf][0], c, 0, 0, 0); \
            c = __builtin_amdgcn_mfma_f32_16x16x32_bf16(A_[mf][0], B_[nf][1], c, 0, 0, 0); \
            c = __builtin_amdgcn_mfma_f32_16x16x32_bf16(A_[mf][1], B_[nf][0], c, 0, 0, 0); \
            c = __builtin_amdgcn_mfma_f32_16x16x32_bf16(A_[mf][0], B_[nf][2], c, 0, 0, 0); \
            c = __builtin_amdgcn_mfma_f32_16x16x32_bf16(A_[mf][1], B_[nf][1], c, 0, 0, 0); \
            c = __builtin_amdgcn_mfma_f32_16x16x32_bf16(A_[mf][2], B_[nf][0], c, 0, 0, 0); \
            acc[mf][nf] = c;                                                  \
        }                                                                     \
    __builtin_amdgcn_s_setprio(0);                                            \
    if ((tt) & 1) {                                                           \
        _Pragma("unroll")                                                     \
        for (int mf = 0; mf < 2; ++mf)                                        \
            _Pragma("unroll")                                                 \
            for (int nf = 0; nf < 4; ++nf) {                                  \
                _Pragma("unroll")                                             \
                for (int r = 0; r < 4; ++r)                                   \
                    mst[mf][nf][r] += (double)acc[mf][nf][r];                 \
                acc[mf][nf] = (f32x4){0.f, 0.f, 0.f, 0.f};                    \
            }                                                                 \
    }                                                                         \
    if ((tt) < NT - 2)       { asm volatile("s_waitcnt vmcnt(6)" ::: "memory"); } \
    else if ((tt) == NT - 2) { asm volatile("s_waitcnt vmcnt(0)" ::: "memory"); } \
    BARRIER;                                                                  \
} while (0)

    for (int tb = 0; tb + 3 <= NT; tb += 3) {
        TILE(tb,     0, 2);
        TILE(tb + 1, 1, 0);
        TILE(tb + 2, 2, 1);
    }
    TILE(30, 0, 2);
    TILE(31, 1, 0);
#undef TILE
#undef PB

    // epilogue: bias in f64, store f32, fused column stats
    double* sdsum = (double*)sm;               // [16][128]
    double* sdsqs = sdsum + 16 * 128;          // [16][128]
    const int grp = wm * 4 + hi;               // 0..15 row-group
#pragma unroll
    for (int nf = 0; nf < 4; ++nf) {
        const int colL = wn * 64 + nf * 16 + l15;   // 0..127
        const int colc = col0 + colL;
        const double bb = (double)bias[colc];
        double s = 0.0, q = 0.0;
#pragma unroll
        for (int mf = 0; mf < 2; ++mf)
#pragma unroll
            for (int r = 0; r < 4; ++r) {
                const int roww = row0 + wm * 32 + mf * 16 + hi * 4 + r;
                const float yval = (float)(mst[mf][nf][r] + bb);
                Y[(size_t)roww * NF + colc] = yval;
                s += (double)yval;
                q += (double)yval * (double)yval;
            }
        sdsum[grp * 128 + colL] = s;
        sdsqs[grp * 128 + colL] = q;
    }
    __syncthreads();
    if (t < 128) {
        double s = 0.0;
#pragma unroll
        for (int g = 0; g < 16; ++g) s += sdsum[g * 128 + t];
        atomicAdd(&dsum[col0 + t], s);
    } else if (t < 256) {
        const int c = t - 128;
        double q = 0.0;
#pragma unroll
        for (int g = 0; g < 16; ++g) q += sdsqs[g * 128 + c];
        atomicAdd(&dsqs[col0 + c], q);
    }
}

// ---------------------------------------------------------------------------
// Kernel 2 (fallback, ws too small): in-kernel split, 6 products (R7 code).
// ---------------------------------------------------------------------------
__global__ __launch_bounds__(512) void gemm_mfma_split(
    const float* __restrict__ X, const float* __restrict__ W,
    const int* __restrict__ Mk, const float* __restrict__ bias,
    float* __restrict__ Y)
{
    __shared__ __align__(16) ushort a0s[128 * 40];
    __shared__ __align__(16) ushort a1s[128 * 40];
    __shared__ __align__(16) ushort a2s[128 * 40];
    __shared__ __align__(16) ushort b0s[128 * 40];
    __shared__ __align__(16) ushort b1s[128 * 40];
    __shared__ __align__(16) ushort b2s[128 * 40];

    const int t = threadIdx.x;
    const int row0 = blockIdx.y * 128;
    const int col0 = blockIdx.x * 128;
    const int srow = t >> 2;
    const int skb  = (t & 3) * 8;

    const float* Xp = X + (size_t)(row0 + srow) * INF + skb;
    const float* Wp = W + (size_t)(col0 + srow) * INF + skb;
    const int*   Mp = Mk + (size_t)(col0 + srow) * INF + skb;

    const int l   = t & 63;
    const int l15 = l & 15;
    const int hi  = l >> 4;
    const int wid = t >> 6;
    const int wm  = wid >> 1;
    const int wn  = wid & 1;

    f32x4  acc[2][4];
    double sh[2][4][4];
#pragma unroll
    for (int mf = 0; mf < 2; ++mf)
#pragma unroll
        for (int nf = 0; nf < 4; ++nf) {
            acc[mf][nf] = (f32x4){0.f, 0.f, 0.f, 0.f};
#pragma unroll
            for (int r = 0; r < 4; ++r) sh[mf][nf][r] = 0.0;
        }

    float4 xA0 = *(const float4*)(Xp);
    float4 xA1 = *(const float4*)(Xp + 4);
    float4 wB0 = *(const float4*)(Wp);
    float4 wB1 = *(const float4*)(Wp + 4);
    int4   mB0 = *(const int4*)(Mp);
    int4   mB1 = *(const int4*)(Mp + 4);

    for (int k0 = 0; k0 < INF; k0 += 32) {
        __syncthreads();
        {
            const float v[8] = {xA0.x, xA0.y, xA0.z, xA0.w, xA1.x, xA1.y, xA1.z, xA1.w};
            short8v s0, s1, s2;
#pragma unroll
            for (int i = 0; i < 8; ++i) {
                ushort h0, h1, h2;
                split3(v[i], h0, h1, h2);
                s0[i] = (short)h0; s1[i] = (short)h1; s2[i] = (short)h2;
            }
            const int off = srow * 40 + skb;
            *(short8v*)&a0s[off] = s0;
            *(short8v*)&a1s[off] = s1;
            *(short8v*)&a2s[off] = s2;
        }
        {
            const float wv[8] = {wB0.x * (float)mB0.x, wB0.y * (float)mB0.y,
                                 wB0.z * (float)mB0.z, wB0.w * (float)mB0.w,
                                 wB1.x * (float)mB1.x, wB1.y * (float)mB1.y,
                                 wB1.z * (float)mB1.z, wB1.w * (float)mB1.w};
            short8v s0, s1, s2;
#pragma unroll
            for (int i = 0; i < 8; ++i) {
                ushort h0, h1, h2;
                split3(wv[i], h0, h1, h2);
                s0[i] = (short)h0; s1[i] = (short)h1; s2[i] = (short)h2;
            }
            const int off = srow * 40 + skb;
            *(short8v*)&b0s[off] = s0;
            *(short8v*)&b1s[off] = s1;
            *(short8v*)&b2s[off] = s2;
        }
        __syncthreads();

        if (k0 + 32 < INF) {
            const int kn = k0 + 32;
            xA0 = *(const float4*)(Xp + kn);
            xA1 = *(const float4*)(Xp + kn + 4);
            wB0 = *(const float4*)(Wp + kn);
            wB1 = *(const float4*)(Wp + kn + 4);
            mB0 = *(const int4*)(Mp + kn);
            mB1 = *(const int4*)(Mp + kn + 4);
        }

        short8v A[2][3], B[4][3];
#pragma unroll
        for (int mf = 0; mf < 2; ++mf) {
            const int roff = (wm * 32 + mf * 16 + l15) * 40 + hi * 8;
            A[mf][0] = *(const short8v*)&a0s[roff];
            A[mf][1] = *(const short8v*)&a1s[roff];
            A[mf][2] = *(const short8v*)&a2s[roff];
        }
#pragma unroll
        for (int nf = 0; nf < 4; ++nf) {
            const int roff = (wn * 64 + nf * 16 + l15) * 40 + hi * 8;
            B[nf][0] = *(const short8v*)&b0s[roff];
            B[nf][1] = *(const short8v*)&b1s[roff];
            B[nf][2] = *(const short8v*)&b2s[roff];
        }

#pragma unroll
        for (int mf = 0; mf < 2; ++mf)
#pragma unroll
            for (int nf = 0; nf < 4; ++nf) {
                f32x4 c = acc[mf][nf];
                c = __builtin_amdgcn_mfma_f32_16x16x32_bf16(A[mf][0], B[nf][0], c, 0, 0, 0);
                c = __builtin_amdgcn_mfma_f32_16x16x32_bf16(A[mf][0], B[nf][1], c, 0, 0, 0);
                c = __builtin_amdgcn_mfma_f32_16x16x32_bf16(A[mf][1], B[nf][0], c, 0, 0, 0);
                c = __builtin_amdgcn_mfma_f32_16x16x32_bf16(A[mf][0], B[nf][2], c, 0, 0, 0);
                c = __builtin_amdgcn_mfma_f32_16x16x32_bf16(A[mf][1], B[nf][1], c, 0, 0, 0);
                c = __builtin_amdgcn_mfma_f32_16x16x32_bf16(A[mf][2], B[nf][0], c, 0, 0, 0);
                acc[mf][nf] = c;
            }

        if (k0 & 32) {
#pragma unroll
            for (int mf = 0; mf < 2; ++mf)
#pragma unroll
                for (int nf = 0; nf < 4; ++nf) {
#pragma unroll
                    for (int r = 0; r < 4; ++r) sh[mf][nf][r] += (double)acc[mf][nf][r];
                    acc[mf][nf] = (f32x4){0.f, 0.f, 0.f, 0.f};
                }
        }
    }

#pragma unroll
    for (int mf = 0; mf < 2; ++mf)
#pragma unroll
        for (int nf = 0; nf < 4; ++nf) {
            const int col = col0 + wn * 64 + nf * 16 + l15;
            const double bb = (double)bias[col];
#pragma unroll
            for (int r = 0; r < 4; ++r) {
                const int row = row0 + wm * 32 + mf * 16 + hi * 4 + r;
                Y[(size_t)row * NF + col] = (float)(sh[mf][nf][r] + bb);
            }
        }
}

// ---------------------------------------------------------------------------
// Kernel 3 (fallback path only): per-column partial sums (f64)
// ---------------------------------------------------------------------------
__global__ __launch_bounds__(256) void stats_partial(
    const float* __restrict__ Y, double* __restrict__ dsum, double* __restrict__ dsqs)
{
    const int col = blockIdx.x * 256 + threadIdx.x;
    const int r0  = blockIdx.y * 256;
    double s = 0.0, ss = 0.0;
    for (int i = 0; i < 256; ++i) {
        const float v = Y[(size_t)(r0 + i) * NF + col];
        s  += (double)v;
        ss += (double)v * (double)v;
    }
    atomicAdd(&dsum[col], s);
    atomicAdd(&dsqs[col], ss);
}

// ---------------------------------------------------------------------------
// Kernel 4: finalize mean / rstd / boost (f64 + f32 copies)
// ---------------------------------------------------------------------------
__global__ __launch_bounds__(256) void stats_final(
    const double* __restrict__ dsum, const double* __restrict__ dsqs,
    const float* __restrict__ duty, const int* __restrict__ kp,
    double* __restrict__ mean64, double* __restrict__ rstd64, double* __restrict__ boost64,
    float* __restrict__ mean32, float* __restrict__ rstd32, float* __restrict__ boost32)
{
    const int c = blockIdx.x * 256 + threadIdx.x;
    const double m   = dsum[c] / (double)BATCH;
    const double var = dsqs[c] / (double)BATCH - m * m;
    const double rs  = 1.0 / sqrt(var + (double)BN_EPS);
    const double td  = (double)(*kp) / (double)NF;
    const double bf  = exp(td - (double)duty[c]);
    mean64[c] = m;  rstd64[c] = rs;  boost64[c] = bf;
    mean32[c] = (float)m; rstd32[c] = (float)rs; boost32[c] = (float)bf;
}

// ---------------------------------------------------------------------------
// Kernel 5 (v4): per-row BN-apply + boosted top-k + f64 band refinement.
// Changes vs R14 (final selection identical):
//  - pass-1 histogram built DURING the load pass, into 4 per-wave copies
//    (hot-bin atomic serialization / 4); one fewer full 4096-sweep.
//  - classify uses the SAVED integer keys with an ulp-domain band
//    (+-2048 ulps >= 6e-5 in value, vs actual boosted-value uncertainty
//    <1e-6); the f64 refinement picks the exact top-K among candidates,
//    so any band >= uncertainty yields the same selection.
// ---------------------------------------------------------------------------
#define MAXCAND 64
#define LCAP 768
#define BANDK 2048u

__global__ __launch_bounds__(256) void topk_kernel(
    const float* __restrict__ mean32, const float* __restrict__ rstd32,
    const float* __restrict__ boost32,
    const double* __restrict__ mean64, const double* __restrict__ rstd64,
    const double* __restrict__ boost64,
    const int* __restrict__ kp,
    const float* __restrict__ X, const float* __restrict__ W,
    const int* __restrict__ Mk, const float* __restrict__ bias,
    float* __restrict__ Y)
{
    __shared__ float    yv[NF];
    __shared__ unsigned keys[NF];
    __shared__ unsigned histw[4][256];
    __shared__ unsigned hist[256];
    __shared__ unsigned scan[256];
    __shared__ unsigned wtot[4];
    __shared__ unsigned s_bin, s_below;
    __shared__ int      s_cnt;
    __shared__ unsigned lkey[LCAP];
    __shared__ double   red[256];
    __shared__ int      s_ncand, s_H;
    __shared__ int      cand_idx[MAXCAND];
    __shared__ double   cand_val[MAXCAND];
    __shared__ unsigned char cand_pick[MAXCAND];

    const int r = blockIdx.x;
    const int t = threadIdx.x;
    const int K = *kp;
    const int lane = t & 63;
    const int w    = t >> 6;

    // ---- init per-wave hists ----
#pragma unroll
    for (int ww = 0; ww < 4; ++ww) histw[ww][t] = 0u;
    if (t == 0) s_cnt = 0;
    __syncthreads();

    // ---- load row, BN, keys + per-wave top-byte histogram (one pass) ----
    for (int j = 0; j < 4; ++j) {
        const int n = j * 1024 + t * 4;
        const float4 v  = *(const float4*)&Y[(size_t)r * NF + n];
        const float4 mm = *(const float4*)&mean32[n];
        const float4 rs = *(const float4*)&rstd32[n];
        const float4 bo = *(const float4*)&boost32[n];
        const float yb[4] = {(v.x - mm.x) * rs.x, (v.y - mm.y) * rs.y,
                             (v.z - mm.z) * rs.z, (v.w - mm.w) * rs.w};
        const float bsv[4] = {yb[0] * bo.x, yb[1] * bo.y, yb[2] * bo.z, yb[3] * bo.w};
#pragma unroll
        for (int q = 0; q < 4; ++q) {
            yv[n + q] = yb[q];
            unsigned u = __float_as_uint(bsv[q]);
            u ^= (u & 0x80000000u) ? 0xFFFFFFFFu : 0x80000000u;
            keys[n + q] = u;
            atomicAdd(&histw[w][u >> 24], 1u);
        }
    }
    __syncthreads();

#define SUFFIX_SCAN(V0) do {                                                  \
    unsigned v_ = (V0);                                                       \
    _Pragma("unroll")                                                         \
    for (int off_ = 1; off_ < 64; off_ <<= 1) {                               \
        const unsigned o_ = __shfl_down(v_, off_, 64);                        \
        if (lane + off_ < 64) v_ += o_;                                       \
    }                                                                         \
    if (lane == 0) wtot[w] = v_;                                              \
    __syncthreads();                                                          \
    unsigned add_ = 0;                                                        \
    for (int ww_ = w + 1; ww_ < 4; ++ww_) add_ += wtot[ww_];                  \
    scan[t] = v_ + add_;                                                      \
    __syncthreads();                                                          \
} while (0)

    // ---- pass 1 selection (hist = sum of 4 per-wave copies) ----
    const unsigned h1v = histw[0][t] + histw[1][t] + histw[2][t] + histw[3][t];
    SUFFIX_SCAN(h1v);
    int remaining = K;
    if (scan[t] >= (unsigned)remaining &&
        (t == 255 || scan[t + 1] < (unsigned)remaining)) {
        s_bin = (unsigned)t;
        s_below = (t == 255) ? 0u : scan[t + 1];
    }
    __syncthreads();
    const unsigned b1 = s_bin;
    unsigned curval = b1 << 24;
    unsigned curmask = 0xFF000000u;
    remaining -= (int)s_below;
    __syncthreads();

    // ---- compact boundary-bin keys (expected ~550, cap 768) ----
    for (int j = 0; j < 16; ++j) {
        const unsigned u = keys[j * 256 + t];
        if ((u >> 24) == b1) {
            const int slot = atomicAdd(&s_cnt, 1);
            if (slot < LCAP) lkey[slot] = u;
        }
    }
    __syncthreads();
    const bool smallbin = (s_cnt <= LCAP);
    const int cnt = smallbin ? s_cnt : 0;

    // ---- passes 2..4 over compacted list (full-scan fallback) ----
    for (int pass = 2; pass >= 0; --pass) {
        const int sh = pass * 8;
        hist[t] = 0u;
        __syncthreads();
        if (smallbin) {
            for (int i = t; i < cnt; i += 256) {
                const unsigned u = lkey[i];
                if ((u & curmask) == curval)
                    atomicAdd(&hist[(u >> sh) & 255u], 1u);
            }
        } else {
            for (int j = 0; j < 16; ++j) {
                const unsigned u = keys[j * 256 + t];
                if ((u & curmask) == curval)
                    atomicAdd(&hist[(u >> sh) & 255u], 1u);
            }
        }
        __syncthreads();
        SUFFIX_SCAN(hist[t]);
        if (scan[t] >= (unsigned)remaining &&
            (t == 255 || scan[t + 1] < (unsigned)remaining)) {
            s_bin = (unsigned)t;
            s_below = (t == 255) ? 0u : scan[t + 1];
        }
        __syncthreads();
        curval |= (s_bin << sh);
        curmask |= (255u << sh);
        remaining -= (int)s_below;
        __syncthreads();
    }
#undef SUFFIX_SCAN

    const unsigned T = curval;

    // ---- classify + flag via saved integer keys (one pass) ----
    if (t == 0) { s_ncand = 0; s_H = 0; }
    __syncthreads();
    int locH = 0;
    for (int j = 0; j < 16; ++j) {
        const int n = j * 256 + t;
        const unsigned u = keys[n];
        unsigned fl = 0u;
        if (u > T + BANDK) {
            locH++;
            fl = 1u;
        } else if (u + BANDK >= T) {
            const int slot = atomicAdd(&s_ncand, 1);
            if (slot < MAXCAND) cand_idx[slot] = n;
        }
        keys[n] = fl;
    }
    atomicAdd(&s_H, locH);
    __syncthreads();
    const int H = s_H;
    const bool overflow = (s_ncand > MAXCAND);
    const int ncand = overflow ? MAXCAND : s_ncand;
    int need = K - H;
    if (need < 0) need = 0;

    if (!overflow) {
        // f64 band refinement: exact recompute of candidates
        for (int c = 0; c < ncand; ++c) {
            const int n = cand_idx[c];
            const float* xr = X + (size_t)r * INF;
            const float* wn = W + (size_t)n * INF;
            const int*   mn = Mk + (size_t)n * INF;
            double s = 0.0;
            for (int i = t; i < INF; i += 256)
                s += (double)xr[i] * (double)(wn[i] * (float)mn[i]);
            red[t] = s;
            __syncthreads();
            for (int off = 128; off > 0; off >>= 1) {
                if (t < off) red[t] += red[t + off];
                __syncthreads();
            }
            if (t == 0) {
                const double y64 = red[0] + (double)bias[n];
                cand_val[c] = (y64 - mean64[n]) * rstd64[n] * boost64[n];
                cand_pick[c] = 0;
            }
            __syncthreads();
        }
        if (t == 0) {
            for (int p = 0; p < need; ++p) {
                int best = -1;
                for (int c = 0; c < ncand; ++c) {
                    if (cand_pick[c]) continue;
                    if (best < 0 || cand_val[c] > cand_val[best] ||
                        (cand_val[c] == cand_val[best] && cand_idx[c] < cand_idx[best]))
                        best = c;
                }
                if (best < 0) break;
                cand_pick[best] = 1;
            }
        }
        __syncthreads();
        if (t < ncand && cand_pick[t]) keys[cand_idx[t]] = 1u;
        __syncthreads();
    } else {
        // fallback: pure f32 stable selection; recompute key bits inline
        const int fneed = remaining;
        unsigned cntk = 0u;
        for (int j = 0; j < 16; ++j) {
            const int n = t * 16 + j;
            unsigned u = __float_as_uint(yv[n] * boost32[n]);
            u ^= (u & 0x80000000u) ? 0xFFFFFFFFu : 0x80000000u;
            cntk += (u == T) ? 1u : 0u;
        }
        scan[t] = cntk;
        __syncthreads();
        for (int off = 1; off < 256; off <<= 1) {
            const unsigned add = (t >= off) ? scan[t - off] : 0u;
            __syncthreads();
            scan[t] += add;
            __syncthreads();
        }
        unsigned rank = scan[t] - cntk;
        for (int j = 0; j < 16; ++j) {
            const int n = t * 16 + j;
            unsigned u = __float_as_uint(yv[n] * boost32[n]);
            u ^= (u & 0x80000000u) ? 0xFFFFFFFFu : 0x80000000u;
            bool sel;
            if (u == T) { sel = ((int)rank < fneed); rank++; }
            else        { sel = (u > T); }
            keys[n] = sel ? 1u : 0u;
        }
        __syncthreads();
    }

    // ---- vectorized in-place write ----
    for (int j = 0; j < 4; ++j) {
        const int n = j * 1024 + t * 4;
        float4 o;
        o.x = keys[n + 0] ? yv[n + 0] : 0.0f;
        o.y = keys[n + 1] ? yv[n + 1] : 0.0f;
        o.z = keys[n + 2] ? yv[n + 2] : 0.0f;
        o.w = keys[n + 3] ? yv[n + 3] : 0.0f;
        *(float4*)&Y[(size_t)r * NF + n] = o;
    }
}

// ---------------------------------------------------------------------------
extern "C" void kernel_launch(void* const* d_in, const int* in_sizes, int n_in,
                              void* d_out, int out_size, void* d_ws, size_t ws_size,
                              hipStream_t stream)
{
    const float* x     = (const float*)d_in[0];
    const float* W     = (const float*)d_in[1];
    const float* b     = (const float*)d_in[2];
    const int*   wmask = (const int*)d_in[3];
    const float* duty  = (const float*)d_in[4];
    const int*   kp    = (const int*)d_in[5];
    float* out = (float*)d_out;

    const size_t SPLIT_X_ELTS = (size_t)3 * BATCH * INF;   // ushorts
    const size_t SPLIT_W_ELTS = (size_t)3 * NF * INF;
    const size_t STATS_BYTES  = (size_t)5 * NF * sizeof(double) + (size_t)3 * NF * sizeof(float);
    const size_t NEED_FAST    = (SPLIT_X_ELTS + SPLIT_W_ELTS) * sizeof(ushort) + STATS_BYTES;
    const bool fast = (ws_size >= NEED_FAST);

    ushort* xs  = (ushort*)d_ws;
    ushort* wsp = xs + SPLIT_X_ELTS;
    char* statbase = fast ? (char*)(wsp + SPLIT_W_ELTS) : (char*)d_ws;

    double* dsum    = (double*)statbase;     // [4096]
    double* dsqs    = dsum + NF;             // [4096]
    double* mean64  = dsqs + NF;             // [4096]
    double* rstd64  = mean64 + NF;           // [4096]
    double* boost64 = rstd64 + NF;           // [4096]
    float*  mean32  = (float*)(boost64 + NF);
    float*  rstd32  = mean32 + NF;
    float*  boost32 = rstd32 + NF;

    if (fast) {
        hipLaunchKernelGGL(prep_kernel, dim3(6144), dim3(256), 0, stream,
                           x, W, wmask, xs, wsp, dsum);
        hipFuncSetAttribute((const void*)gemm_mfma_fuse,
                            hipFuncAttributeMaxDynamicSharedMemorySize, 147456);
        hipLaunchKernelGGL(gemm_mfma_fuse, dim3(NF / 128, BATCH / 128), dim3(512), 147456,
                           stream, xs, wsp, b, out, dsum, dsqs);
    } else {
        hipLaunchKernelGGL(zero_ws, dim3(2 * NF / 256), dim3(256), 0, stream, dsum);
        hipLaunchKernelGGL(gemm_mfma_split, dim3(NF / 128, BATCH / 128), dim3(512), 0, stream,
                           x, W, wmask, b, out);
        hipLaunchKernelGGL(stats_partial, dim3(NF / 256, BATCH / 256), dim3(256), 0, stream,
                           out, dsum, dsqs);
    }

    hipLaunchKernelGGL(stats_final, dim3(NF / 256), dim3(256), 0, stream,
                       dsum, dsqs, duty, kp,
                       mean64, rstd64, boost64, mean32, rstd32, boost32);
    hipLaunchKernelGGL(topk_kernel, dim3(BATCH), dim3(256), 0, stream,
                       mean32, rstd32, boost32, mean64, rstd64, boost64, kp,
                       x, W, wmask, b, out);
}

// Round 16
// 548.636 us; speedup vs baseline: 1.0589x; 1.0589x over previous
//
#include <hip/hip_runtime.h>

// Problem constants (fixed-shape: B=8192, IN=1024, N=4096, K=409)
#define BATCH 8192
#define INF   1024
#define NF    4096
#define BN_EPS 1e-5
#define NT    32     // K tiles of 32 (all 6 plane-products per tile)

typedef __attribute__((ext_vector_type(8))) short short8v;
typedef __attribute__((ext_vector_type(4))) float f32x4;

#define FENCE asm volatile("" ::: "memory")
#define BARRIER do { FENCE; __builtin_amdgcn_s_barrier(); FENCE; } while (0)

// ---------------------------------------------------------------------------
// Exact 3-way bf16 truncation split: x == bf16(h0)+bf16(h1)+bf16(h2) EXACTLY.
// ---------------------------------------------------------------------------
__device__ __forceinline__ void split3(float x, ushort& h0, ushort& h1, ushort& h2) {
    const unsigned u0 = __float_as_uint(x) & 0xFFFF0000u;
    const float    r1 = x - __uint_as_float(u0);
    const unsigned u1 = __float_as_uint(r1) & 0xFFFF0000u;
    const float    r2 = r1 - __uint_as_float(u1);
    h0 = (ushort)(u0 >> 16);
    h1 = (ushort)(u1 >> 16);
    h2 = (ushort)(__float_as_uint(r2) >> 16);
}

// ---------------------------------------------------------------------------
// Kernel 1 (fast path): merged prep — zero stats (block 0) + pre-split X
// (blocks [0,4096)) and masked W (blocks [4096,6144)) into 3 bf16 planes.
// ---------------------------------------------------------------------------
__global__ __launch_bounds__(256) void prep_kernel(
    const float* __restrict__ X, const float* __restrict__ W,
    const int* __restrict__ Mk,
    ushort* __restrict__ xs, ushort* __restrict__ wsp,
    double* __restrict__ dz)
{
    const int blk = blockIdx.x;
    const int t   = threadIdx.x;
    if (blk == 0) {
#pragma unroll
        for (int i = 0; i < 32; ++i) dz[i * 256 + t] = 0.0;   // 2*NF doubles
    }
    if (blk < 4096) {
        const size_t base = ((size_t)blk * 256 + t) * 8;
        const size_t LS = (size_t)BATCH * INF;
        const float4 v0 = *(const float4*)(X + base);
        const float4 v1 = *(const float4*)(X + base + 4);
        const float v[8] = {v0.x, v0.y, v0.z, v0.w, v1.x, v1.y, v1.z, v1.w};
        short8v s0, s1, s2;
#pragma unroll
        for (int i = 0; i < 8; ++i) {
            ushort h0, h1, h2;
            split3(v[i], h0, h1, h2);
            s0[i] = (short)h0; s1[i] = (short)h1; s2[i] = (short)h2;
        }
        *(short8v*)&xs[base]          = s0;
        *(short8v*)&xs[base + LS]     = s1;
        *(short8v*)&xs[base + 2 * LS] = s2;
    } else {
        const size_t base = ((size_t)(blk - 4096) * 256 + t) * 8;
        const size_t LS = (size_t)NF * INF;
        const float4 v0 = *(const float4*)(W + base);
        const float4 v1 = *(const float4*)(W + base + 4);
        const int4   m0 = *(const int4*)(Mk + base);
        const int4   m1 = *(const int4*)(Mk + base + 4);
        const float v[8] = {v0.x * (float)m0.x, v0.y * (float)m0.y,
                            v0.z * (float)m0.z, v0.w * (float)m0.w,
                            v1.x * (float)m1.x, v1.y * (float)m1.y,
                            v1.z * (float)m1.z, v1.w * (float)m1.w};
        short8v s0, s1, s2;
#pragma unroll
        for (int i = 0; i < 8; ++i) {
            ushort h0, h1, h2;
            split3(v[i], h0, h1, h2);
            s0[i] = (short)h0; s1[i] = (short)h1; s2[i] = (short)h2;
        }
        *(short8v*)&wsp[base]          = s0;
        *(short8v*)&wsp[base + LS]     = s1;
        *(short8v*)&wsp[base + 2 * LS] = s2;
    }
}

// ---------------------------------------------------------------------------
// Kernel 1 (fallback): zero the f64 stats accumulators
// ---------------------------------------------------------------------------
__global__ void zero_ws(double* __restrict__ p) {
    p[blockIdx.x * 256 + threadIdx.x] = 0.0;
}

// ---------------------------------------------------------------------------
// direct global->LDS 16B staging
// ---------------------------------------------------------------------------
__device__ __forceinline__ void gload16(const ushort* g, ushort* l) {
    __builtin_amdgcn_global_load_lds(
        (const __attribute__((address_space(1))) void*)g,
        (__attribute__((address_space(3))) void*)l, 16, 0, 0);
}

// ---------------------------------------------------------------------------
// Kernel 2 (fast path): R12-R14's proven GEMM (MfmaUtil ~49%, 0 conflicts)
// + fused column-stats epilogue. FROZEN.
// ---------------------------------------------------------------------------
__global__ __launch_bounds__(512) void gemm_mfma_fuse(
    const ushort* __restrict__ Xs, const ushort* __restrict__ Wsp,
    const float* __restrict__ bias, float* __restrict__ Y,
    double* __restrict__ dsum, double* __restrict__ dsqs)
{
    extern __shared__ ushort sm[];   // 3 bufs x 6 planes x 4096 ushorts = 144KB
    const size_t LSX = (size_t)BATCH * INF;
    const size_t LSW = (size_t)NF * INF;

    const int t    = threadIdx.x;
    const int row0 = blockIdx.y * 128;
    const int col0 = blockIdx.x * 128;

    const int l   = t & 63;
    const int l15 = l & 15;
    const int hi  = l >> 4;
    const int wid = t >> 6;
    const int wm  = wid >> 1;        // 0..3 -> M offset wm*32
    const int wn  = wid & 1;         // 0..1 -> N offset wn*64

    const int srow  = t >> 2;                      // 0..127
    const int sunit = (t & 3) ^ ((t >> 3) & 3);    // swizzled source 16B-unit
    const int uoff = (hi ^ ((l15 >> 1) & 3)) << 3; // swizzled ds_read unit

    f32x4  acc[2][4];
    double mst[2][4][4];
#pragma unroll
    for (int mf = 0; mf < 2; ++mf)
#pragma unroll
        for (int nf = 0; nf < 4; ++nf) {
            acc[mf][nf] = (f32x4){0.f, 0.f, 0.f, 0.f};
#pragma unroll
            for (int r = 0; r < 4; ++r) mst[mf][nf][r] = 0.0;
        }

#define PB(b, p) (sm + (b) * 24576 + (p) * 4096)

#pragma unroll
    for (int tt = 0; tt < 2; ++tt) {
#pragma unroll
        for (int p = 0; p < 3; ++p)
            gload16(Xs + (size_t)p * LSX + (size_t)(row0 + srow) * INF + tt * 32 + sunit * 8,
                    PB(tt, p) + (size_t)t * 8);
#pragma unroll
        for (int p = 0; p < 3; ++p)
            gload16(Wsp + (size_t)p * LSW + (size_t)(col0 + srow) * INF + tt * 32 + sunit * 8,
                    PB(tt, 3 + p) + (size_t)t * 8);
    }
    asm volatile("s_waitcnt vmcnt(6)" ::: "memory");
    BARRIER;

#define TILE(tt, CUR, DST) do {                                               \
    if ((tt) + 2 < NT) {                                                      \
        const int kof_ = ((tt) + 2) * 32;                                     \
        _Pragma("unroll")                                                     \
        for (int p = 0; p < 3; ++p)                                           \
            gload16(Xs + (size_t)p * LSX + (size_t)(row0 + srow) * INF + kof_ + sunit * 8, \
                    PB(DST, p) + (size_t)t * 8);                              \
        _Pragma("unroll")                                                     \
        for (int p = 0; p < 3; ++p)                                           \
            gload16(Wsp + (size_t)p * LSW + (size_t)(col0 + srow) * INF + kof_ + sunit * 8, \
                    PB(DST, 3 + p) + (size_t)t * 8);                          \
    }                                                                         \
    short8v A_[2][3], B_[4][3];                                               \
    _Pragma("unroll")                                                         \
    for (int mf = 0; mf < 2; ++mf) {                                          \
        const int ra = (wm * 32 + mf * 16 + l15) * 32 + uoff;                 \
        _Pragma("unroll")                                                     \
        for (int p = 0; p < 3; ++p)                                           \
            A_[mf][p] = *(const short8v*)&PB(CUR, p)[ra];                     \
    }                                                                         \
    _Pragma("unroll")                                                         \
    for (int nf = 0; nf < 4; ++nf) {                                          \
        const int rb = (wn * 64 + nf * 16 + l15) * 32 + uoff;                 \
        _Pragma("unroll")                                                     \
        for (int p = 0; p < 3; ++p)                                           \
            B_[nf][p] = *(const short8v*)&PB(CUR, 3 + p)[rb];                 \
    }                                                                         \
    __builtin_amdgcn_s_setprio(1);                                            \
    _Pragma("unroll")                                                         \
    for (int mf = 0; mf < 2; ++mf)                                            \
        _Pragma("unroll")                                                     \
        for (int nf = 0; nf < 4; ++nf) {                                      \
            f32x4 c = acc[mf][nf];                                            \
            c = __builtin_amdgcn_mfma_f32_16x16x32_bf16(A_[mf][0], B_[nf][0], c, 0, 0, 0); \
            c = __builtin_amdgcn_mfma_f32_16x16x32_bf16(A_[mf][0], B_[nf][1], c, 0, 0, 0); \
            c = __builtin_amdgcn_mfma_f32_16x16x32_bf16(A_[mf][1], B_[nf][0], c, 0, 0, 0); \
            c = __builtin_amdgcn_mfma_f32_16x16x32_bf16(A_[mf][0], B_[nf][2], c, 0, 0, 0); \
            c = __builtin_amdgcn_mfma_f32_16x16x32_bf16(A_[mf][1], B_[nf][1], c, 0, 0, 0); \
            c = __builtin_amdgcn_mfma_f32_16x16x32_bf16(A_[mf][2], B_[nf][0], c, 0, 0, 0); \
            acc[mf][nf] = c;                                                  \
        }                                                                     \
    __builtin_amdgcn_s_setprio(0);                                            \
    if ((tt) & 1) {                                                           \
        _Pragma("unroll")                                                     \
        for (int mf = 0; mf < 2; ++mf)                                        \
            _Pragma("unroll")                                                 \
            for (int nf = 0; nf < 4; ++nf) {                                  \
                _Pragma("unroll")                                             \
                for (int r = 0; r < 4; ++r)                                   \
                    mst[mf][nf][r] += (double)acc[mf][nf][r];                 \
                acc[mf][nf] = (f32x4){0.f, 0.f, 0.f, 0.f};                    \
            }                                                                 \
    }                                                                         \
    if ((tt) < NT - 2)       { asm volatile("s_waitcnt vmcnt(6)" ::: "memory"); } \
    else if ((tt) == NT - 2) { asm volatile("s_waitcnt vmcnt(0)" ::: "memory"); } \
    BARRIER;                                                                  \
} while (0)

    for (int tb = 0; tb + 3 <= NT; tb += 3) {
        TILE(tb,     0, 2);
        TILE(tb + 1, 1, 0);
        TILE(tb + 2, 2, 1);
    }
    TILE(30, 0, 2);
    TILE(31, 1, 0);
#undef TILE
#undef PB

    // epilogue: bias in f64, store f32, fused column stats
    double* sdsum = (double*)sm;               // [16][128]
    double* sdsqs = sdsum + 16 * 128;          // [16][128]
    const int grp = wm * 4 + hi;               // 0..15 row-group
#pragma unroll
    for (int nf = 0; nf < 4; ++nf) {
        const int colL = wn * 64 + nf * 16 + l15;   // 0..127
        const int colc = col0 + colL;
        const double bb = (double)bias[colc];
        double s = 0.0, q = 0.0;
#pragma unroll
        for (int mf = 0; mf < 2; ++mf)
#pragma unroll
            for (int r = 0; r < 4; ++r) {
                const int roww = row0 + wm * 32 + mf * 16 + hi * 4 + r;
                const float yval = (float)(mst[mf][nf][r] + bb);
                Y[(size_t)roww * NF + colc] = yval;
                s += (double)yval;
                q += (double)yval * (double)yval;
            }
        sdsum[grp * 128 + colL] = s;
        sdsqs[grp * 128 + colL] = q;
    }
    __syncthreads();
    if (t < 128) {
        double s = 0.0;
#pragma unroll
        for (int g = 0; g < 16; ++g) s += sdsum[g * 128 + t];
        atomicAdd(&dsum[col0 + t], s);
    } else if (t < 256) {
        const int c = t - 128;
        double q = 0.0;
#pragma unroll
        for (int g = 0; g < 16; ++g) q += sdsqs[g * 128 + c];
        atomicAdd(&dsqs[col0 + c], q);
    }
}

// ---------------------------------------------------------------------------
// Kernel 2 (fallback, ws too small): in-kernel split, 6 products (R7 code).
// ---------------------------------------------------------------------------
__global__ __launch_bounds__(512) void gemm_mfma_split(
    const float* __restrict__ X, const float* __restrict__ W,
    const int* __restrict__ Mk, const float* __restrict__ bias,
    float* __restrict__ Y)
{
    __shared__ __align__(16) ushort a0s[128 * 40];
    __shared__ __align__(16) ushort a1s[128 * 40];
    __shared__ __align__(16) ushort a2s[128 * 40];
    __shared__ __align__(16) ushort b0s[128 * 40];
    __shared__ __align__(16) ushort b1s[128 * 40];
    __shared__ __align__(16) ushort b2s[128 * 40];

    const int t = threadIdx.x;
    const int row0 = blockIdx.y * 128;
    const int col0 = blockIdx.x * 128;
    const int srow = t >> 2;
    const int skb  = (t & 3) * 8;

    const float* Xp = X + (size_t)(row0 + srow) * INF + skb;
    const float* Wp = W + (size_t)(col0 + srow) * INF + skb;
    const int*   Mp = Mk + (size_t)(col0 + srow) * INF + skb;

    const int l   = t & 63;
    const int l15 = l & 15;
    const int hi  = l >> 4;
    const int wid = t >> 6;
    const int wm  = wid >> 1;
    const int wn  = wid & 1;

    f32x4  acc[2][4];
    double sh[2][4][4];
#pragma unroll
    for (int mf = 0; mf < 2; ++mf)
#pragma unroll
        for (int nf = 0; nf < 4; ++nf) {
            acc[mf][nf] = (f32x4){0.f, 0.f, 0.f, 0.f};
#pragma unroll
            for (int r = 0; r < 4; ++r) sh[mf][nf][r] = 0.0;
        }

    float4 xA0 = *(const float4*)(Xp);
    float4 xA1 = *(const float4*)(Xp + 4);
    float4 wB0 = *(const float4*)(Wp);
    float4 wB1 = *(const float4*)(Wp + 4);
    int4   mB0 = *(const int4*)(Mp);
    int4   mB1 = *(const int4*)(Mp + 4);

    for (int k0 = 0; k0 < INF; k0 += 32) {
        __syncthreads();
        {
            const float v[8] = {xA0.x, xA0.y, xA0.z, xA0.w, xA1.x, xA1.y, xA1.z, xA1.w};
            short8v s0, s1, s2;
#pragma unroll
            for (int i = 0; i < 8; ++i) {
                ushort h0, h1, h2;
                split3(v[i], h0, h1, h2);
                s0[i] = (short)h0; s1[i] = (short)h1; s2[i] = (short)h2;
            }
            const int off = srow * 40 + skb;
            *(short8v*)&a0s[off] = s0;
            *(short8v*)&a1s[off] = s1;
            *(short8v*)&a2s[off] = s2;
        }
        {
            const float wv[8] = {wB0.x * (float)mB0.x, wB0.y * (float)mB0.y,
                                 wB0.z * (float)mB0.z, wB0.w * (float)mB0.w,
                                 wB1.x * (float)mB1.x, wB1.y * (float)mB1.y,
                                 wB1.z * (float)mB1.z, wB1.w * (float)mB1.w};
            short8v s0, s1, s2;
#pragma unroll
            for (int i = 0; i < 8; ++i) {
                ushort h0, h1, h2;
                split3(wv[i], h0, h1, h2);
                s0[i] = (short)h0; s1[i] = (short)h1; s2[i] = (short)h2;
            }
            const int off = srow * 40 + skb;
            *(short8v*)&b0s[off] = s0;
            *(short8v*)&b1s[off] = s1;
            *(short8v*)&b2s[off] = s2;
        }
        __syncthreads();

        if (k0 + 32 < INF) {
            const int kn = k0 + 32;
            xA0 = *(const float4*)(Xp + kn);
            xA1 = *(const float4*)(Xp + kn + 4);
            wB0 = *(const float4*)(Wp + kn);
            wB1 = *(const float4*)(Wp + kn + 4);
            mB0 = *(const int4*)(Mp + kn);
            mB1 = *(const int4*)(Mp + kn + 4);
        }

        short8v A[2][3], B[4][3];
#pragma unroll
        for (int mf = 0; mf < 2; ++mf) {
            const int roff = (wm * 32 + mf * 16 + l15) * 40 + hi * 8;
            A[mf][0] = *(const short8v*)&a0s[roff];
            A[mf][1] = *(const short8v*)&a1s[roff];
            A[mf][2] = *(const short8v*)&a2s[roff];
        }
#pragma unroll
        for (int nf = 0; nf < 4; ++nf) {
            const int roff = (wn * 64 + nf * 16 + l15) * 40 + hi * 8;
            B[nf][0] = *(const short8v*)&b0s[roff];
            B[nf][1] = *(const short8v*)&b1s[roff];
            B[nf][2] = *(const short8v*)&b2s[roff];
        }

#pragma unroll
        for (int mf = 0; mf < 2; ++mf)
#pragma unroll
            for (int nf = 0; nf < 4; ++nf) {
                f32x4 c = acc[mf][nf];
                c = __builtin_amdgcn_mfma_f32_16x16x32_bf16(A[mf][0], B[nf][0], c, 0, 0, 0);
                c = __builtin_amdgcn_mfma_f32_16x16x32_bf16(A[mf][0], B[nf][1], c, 0, 0, 0);
                c = __builtin_amdgcn_mfma_f32_16x16x32_bf16(A[mf][1], B[nf][0], c, 0, 0, 0);
                c = __builtin_amdgcn_mfma_f32_16x16x32_bf16(A[mf][0], B[nf][2], c, 0, 0, 0);
                c = __builtin_amdgcn_mfma_f32_16x16x32_bf16(A[mf][1], B[nf][1], c, 0, 0, 0);
                c = __builtin_amdgcn_mfma_f32_16x16x32_bf16(A[mf][2], B[nf][0], c, 0, 0, 0);
                acc[mf][nf] = c;
            }

        if (k0 & 32) {
#pragma unroll
            for (int mf = 0; mf < 2; ++mf)
#pragma unroll
                for (int nf = 0; nf < 4; ++nf) {
#pragma unroll
                    for (int r = 0; r < 4; ++r) sh[mf][nf][r] += (double)acc[mf][nf][r];
                    acc[mf][nf] = (f32x4){0.f, 0.f, 0.f, 0.f};
                }
        }
    }

#pragma unroll
    for (int mf = 0; mf < 2; ++mf)
#pragma unroll
        for (int nf = 0; nf < 4; ++nf) {
            const int col = col0 + wn * 64 + nf * 16 + l15;
            const double bb = (double)bias[col];
#pragma unroll
            for (int r = 0; r < 4; ++r) {
                const int row = row0 + wm * 32 + mf * 16 + hi * 4 + r;
                Y[(size_t)row * NF + col] = (float)(sh[mf][nf][r] + bb);
            }
        }
}

// ---------------------------------------------------------------------------
// Kernel 3 (fallback path only): per-column partial sums (f64)
// ---------------------------------------------------------------------------
__global__ __launch_bounds__(256) void stats_partial(
    const float* __restrict__ Y, double* __restrict__ dsum, double* __restrict__ dsqs)
{
    const int col = blockIdx.x * 256 + threadIdx.x;
    const int r0  = blockIdx.y * 256;
    double s = 0.0, ss = 0.0;
    for (int i = 0; i < 256; ++i) {
        const float v = Y[(size_t)(r0 + i) * NF + col];
        s  += (double)v;
        ss += (double)v * (double)v;
    }
    atomicAdd(&dsum[col], s);
    atomicAdd(&dsqs[col], ss);
}

// ---------------------------------------------------------------------------
// Kernel 4: finalize mean / rstd / boost (f64 + f32 copies)
// ---------------------------------------------------------------------------
__global__ __launch_bounds__(256) void stats_final(
    const double* __restrict__ dsum, const double* __restrict__ dsqs,
    const float* __restrict__ duty, const int* __restrict__ kp,
    double* __restrict__ mean64, double* __restrict__ rstd64, double* __restrict__ boost64,
    float* __restrict__ mean32, float* __restrict__ rstd32, float* __restrict__ boost32)
{
    const int c = blockIdx.x * 256 + threadIdx.x;
    const double m   = dsum[c] / (double)BATCH;
    const double var = dsqs[c] / (double)BATCH - m * m;
    const double rs  = 1.0 / sqrt(var + (double)BN_EPS);
    const double td  = (double)(*kp) / (double)NF;
    const double bf  = exp(td - (double)duty[c]);
    mean64[c] = m;  rstd64[c] = rs;  boost64[c] = bf;
    mean32[c] = (float)m; rstd32[c] = (float)rs; boost32[c] = (float)bf;
}

// ---------------------------------------------------------------------------
// Kernel 5 (v3 — R14's proven 548us version, restored): per-row BN-apply +
// boosted top-k + f64 band refinement. R15's v4 regressed (extra 5KB LDS
// crossed the 4->3 blocks/CU occupancy boundary); v3 restored verbatim.
// ---------------------------------------------------------------------------
#define BAND 1e-4f
#define MAXCAND 64
#define LCAP 768

__global__ __launch_bounds__(256) void topk_kernel(
    const float* __restrict__ mean32, const float* __restrict__ rstd32,
    const float* __restrict__ boost32,
    const double* __restrict__ mean64, const double* __restrict__ rstd64,
    const double* __restrict__ boost64,
    const int* __restrict__ kp,
    const float* __restrict__ X, const float* __restrict__ W,
    const int* __restrict__ Mk, const float* __restrict__ bias,
    float* __restrict__ Y)
{
    __shared__ float    yv[NF];
    __shared__ unsigned keys[NF];
    __shared__ unsigned hist[256];
    __shared__ unsigned scan[256];
    __shared__ unsigned wtot[4];
    __shared__ unsigned s_bin, s_below;
    __shared__ int      s_cnt;
    __shared__ unsigned lkey[LCAP];
    __shared__ double   red[256];
    __shared__ int      s_ncand, s_H;
    __shared__ int      cand_idx[MAXCAND];
    __shared__ double   cand_val[MAXCAND];
    __shared__ unsigned char cand_pick[MAXCAND];

    const int r = blockIdx.x;
    const int t = threadIdx.x;
    const int K = *kp;
    const int lane = t & 63;
    const int w    = t >> 6;

    // ---- load row, BN, keys (float4 vectorized) ----
    for (int j = 0; j < 4; ++j) {
        const int n = j * 1024 + t * 4;
        const float4 v  = *(const float4*)&Y[(size_t)r * NF + n];
        const float4 mm = *(const float4*)&mean32[n];
        const float4 rs = *(const float4*)&rstd32[n];
        const float4 bo = *(const float4*)&boost32[n];
        const float yb[4] = {(v.x - mm.x) * rs.x, (v.y - mm.y) * rs.y,
                             (v.z - mm.z) * rs.z, (v.w - mm.w) * rs.w};
        const float bsv[4] = {yb[0] * bo.x, yb[1] * bo.y, yb[2] * bo.z, yb[3] * bo.w};
#pragma unroll
        for (int q = 0; q < 4; ++q) {
            yv[n + q] = yb[q];
            unsigned u = __float_as_uint(bsv[q]);
            u ^= (u & 0x80000000u) ? 0xFFFFFFFFu : 0x80000000u;
            keys[n + q] = u;
        }
    }
    __syncthreads();

#define SUFFIX_SCAN() do {                                                    \
    unsigned v_ = hist[t];                                                    \
    _Pragma("unroll")                                                         \
    for (int off_ = 1; off_ < 64; off_ <<= 1) {                               \
        const unsigned o_ = __shfl_down(v_, off_, 64);                        \
        if (lane + off_ < 64) v_ += o_;                                       \
    }                                                                         \
    if (lane == 0) wtot[w] = v_;                                              \
    __syncthreads();                                                          \
    unsigned add_ = 0;                                                        \
    for (int ww_ = w + 1; ww_ < 4; ++ww_) add_ += wtot[ww_];                  \
    scan[t] = v_ + add_;                                                      \
    __syncthreads();                                                          \
} while (0)

    // ---- pass 1: full hist over top byte ----
    hist[t] = 0u;
    __syncthreads();
    for (int j = 0; j < 16; ++j)
        atomicAdd(&hist[keys[j * 256 + t] >> 24], 1u);
    __syncthreads();
    SUFFIX_SCAN();
    int remaining = K;
    if (scan[t] >= (unsigned)remaining &&
        (t == 255 || scan[t + 1] < (unsigned)remaining)) {
        s_bin = (unsigned)t;
        s_below = (t == 255) ? 0u : scan[t + 1];
    }
    if (t == 0) s_cnt = 0;
    __syncthreads();
    const unsigned b1 = s_bin;
    unsigned curval = b1 << 24;
    unsigned curmask = 0xFF000000u;
    remaining -= (int)s_below;
    __syncthreads();

    // ---- compact boundary-bin keys (expected ~550, cap 768) ----
    for (int j = 0; j < 16; ++j) {
        const unsigned u = keys[j * 256 + t];
        if ((u >> 24) == b1) {
            const int slot = atomicAdd(&s_cnt, 1);
            if (slot < LCAP) lkey[slot] = u;
        }
    }
    __syncthreads();
    const bool smallbin = (s_cnt <= LCAP);
    const int cnt = smallbin ? s_cnt : 0;

    // ---- passes 2..4 over compacted list (full-scan fallback) ----
    for (int pass = 2; pass >= 0; --pass) {
        const int sh = pass * 8;
        hist[t] = 0u;
        __syncthreads();
        if (smallbin) {
            for (int i = t; i < cnt; i += 256) {
                const unsigned u = lkey[i];
                if ((u & curmask) == curval)
                    atomicAdd(&hist[(u >> sh) & 255u], 1u);
            }
        } else {
            for (int j = 0; j < 16; ++j) {
                const unsigned u = keys[j * 256 + t];
                if ((u & curmask) == curval)
                    atomicAdd(&hist[(u >> sh) & 255u], 1u);
            }
        }
        __syncthreads();
        SUFFIX_SCAN();
        if (scan[t] >= (unsigned)remaining &&
            (t == 255 || scan[t + 1] < (unsigned)remaining)) {
            s_bin = (unsigned)t;
            s_below = (t == 255) ? 0u : scan[t + 1];
        }
        __syncthreads();
        curval |= (s_bin << sh);
        curmask |= (255u << sh);
        remaining -= (int)s_below;
        __syncthreads();
    }
#undef SUFFIX_SCAN

    const unsigned T = curval;
    const unsigned vT = (T & 0x80000000u) ? (T ^ 0x80000000u) : ~T;
    const float cut32 = __uint_as_float(vT);
    const float cutHi = cut32 + BAND;
    const float cutLo = cut32 - BAND;

    // ---- classify + flag in one pass (flags overwrite keys[]) ----
    if (t == 0) { s_ncand = 0; s_H = 0; }
    __syncthreads();
    int locH = 0;
    for (int j = 0; j < 16; ++j) {
        const int n = j * 256 + t;
        const float b = yv[n] * boost32[n];
        unsigned fl = 0u;
        if (b > cutHi) {
            locH++;
            fl = 1u;
        } else if (b >= cutLo) {
            const int slot = atomicAdd(&s_ncand, 1);
            if (slot < MAXCAND) cand_idx[slot] = n;
        }
        keys[n] = fl;
    }
    atomicAdd(&s_H, locH);
    __syncthreads();
    const int H = s_H;
    const bool overflow = (s_ncand > MAXCAND);
    const int ncand = overflow ? MAXCAND : s_ncand;
    int need = K - H;
    if (need < 0) need = 0;

    if (!overflow) {
        // f64 band refinement: exact recompute of candidates
        for (int c = 0; c < ncand; ++c) {
            const int n = cand_idx[c];
            const float* xr = X + (size_t)r * INF;
            const float* wn = W + (size_t)n * INF;
            const int*   mn = Mk + (size_t)n * INF;
            double s = 0.0;
            for (int i = t; i < INF; i += 256)
                s += (double)xr[i] * (double)(wn[i] * (float)mn[i]);
            red[t] = s;
            __syncthreads();
            for (int off = 128; off > 0; off >>= 1) {
                if (t < off) red[t] += red[t + off];
                __syncthreads();
            }
            if (t == 0) {
                const double y64 = red[0] + (double)bias[n];
                cand_val[c] = (y64 - mean64[n]) * rstd64[n] * boost64[n];
                cand_pick[c] = 0;
            }
            __syncthreads();
        }
        if (t == 0) {
            for (int p = 0; p < need; ++p) {
                int best = -1;
                for (int c = 0; c < ncand; ++c) {
                    if (cand_pick[c]) continue;
                    if (best < 0 || cand_val[c] > cand_val[best] ||
                        (cand_val[c] == cand_val[best] && cand_idx[c] < cand_idx[best]))
                        best = c;
                }
                if (best < 0) break;
                cand_pick[best] = 1;
            }
        }
        __syncthreads();
        if (t < ncand && cand_pick[t]) keys[cand_idx[t]] = 1u;
        __syncthreads();
    } else {
        // fallback: pure f32 stable selection; recompute key bits inline
        const int fneed = remaining;
        unsigned cntk = 0u;
        for (int j = 0; j < 16; ++j) {
            const int n = t * 16 + j;
            unsigned u = __float_as_uint(yv[n] * boost32[n]);
            u ^= (u & 0x80000000u) ? 0xFFFFFFFFu : 0x80000000u;
            cntk += (u == T) ? 1u : 0u;
        }
        scan[t] = cntk;
        __syncthreads();
        for (int off = 1; off < 256; off <<= 1) {
            const unsigned add = (t >= off) ? scan[t - off] : 0u;
            __syncthreads();
            scan[t] += add;
            __syncthreads();
        }
        unsigned rank = scan[t] - cntk;
        for (int j = 0; j < 16; ++j) {
            const int n = t * 16 + j;
            unsigned u = __float_as_uint(yv[n] * boost32[n]);
            u ^= (u & 0x80000000u) ? 0xFFFFFFFFu : 0x80000000u;
            bool sel;
            if (u == T) { sel = ((int)rank < fneed); rank++; }
            else        { sel = (u > T); }
            keys[n] = sel ? 1u : 0u;
        }
        __syncthreads();
    }

    // ---- vectorized in-place write ----
    for (int j = 0; j < 4; ++j) {
        const int n = j * 1024 + t * 4;
        float4 o;
        o.x = keys[n + 0] ? yv[n + 0] : 0.0f;
        o.y = keys[n + 1] ? yv[n + 1] : 0.0f;
        o.z = keys[n + 2] ? yv[n + 2] : 0.0f;
        o.w = keys[n + 3] ? yv[n + 3] : 0.0f;
        *(float4*)&Y[(size_t)r * NF + n] = o;
    }
}

// ---------------------------------------------------------------------------
extern "C" void kernel_launch(void* const* d_in, const int* in_sizes, int n_in,
                              void* d_out, int out_size, void* d_ws, size_t ws_size,
                              hipStream_t stream)
{
    const float* x     = (const float*)d_in[0];
    const float* W     = (const float*)d_in[1];
    const float* b     = (const float*)d_in[2];
    const int*   wmask = (const int*)d_in[3];
    const float* duty  = (const float*)d_in[4];
    const int*   kp    = (const int*)d_in[5];
    float* out = (float*)d_out;

    const size_t SPLIT_X_ELTS = (size_t)3 * BATCH * INF;   // ushorts
    const size_t SPLIT_W_ELTS = (size_t)3 * NF * INF;
    const size_t STATS_BYTES  = (size_t)5 * NF * sizeof(double) + (size_t)3 * NF * sizeof(float);
    const size_t NEED_FAST    = (SPLIT_X_ELTS + SPLIT_W_ELTS) * sizeof(ushort) + STATS_BYTES;
    const bool fast = (ws_size >= NEED_FAST);

    ushort* xs  = (ushort*)d_ws;
    ushort* wsp = xs + SPLIT_X_ELTS;
    char* statbase = fast ? (char*)(wsp + SPLIT_W_ELTS) : (char*)d_ws;

    double* dsum    = (double*)statbase;     // [4096]
    double* dsqs    = dsum + NF;             // [4096]
    double* mean64  = dsqs + NF;             // [4096]
    double* rstd64  = mean64 + NF;           // [4096]
    double* boost64 = rstd64 + NF;           // [4096]
    float*  mean32  = (float*)(boost64 + NF);
    float*  rstd32  = mean32 + NF;
    float*  boost32 = rstd32 + NF;

    if (fast) {
        hipLaunchKernelGGL(prep_kernel, dim3(6144), dim3(256), 0, stream,
                           x, W, wmask, xs, wsp, dsum);
        hipFuncSetAttribute((const void*)gemm_mfma_fuse,
                            hipFuncAttributeMaxDynamicSharedMemorySize, 147456);
        hipLaunchKernelGGL(gemm_mfma_fuse, dim3(NF / 128, BATCH / 128), dim3(512), 147456,
                           stream, xs, wsp, b, out, dsum, dsqs);
    } else {
        hipLaunchKernelGGL(zero_ws, dim3(2 * NF / 256), dim3(256), 0, stream, dsum);
        hipLaunchKernelGGL(gemm_mfma_split, dim3(NF / 128, BATCH / 128), dim3(512), 0, stream,
                           x, W, wmask, b, out);
        hipLaunchKernelGGL(stats_partial, dim3(NF / 256, BATCH / 256), dim3(256), 0, stream,
                           out, dsum, dsqs);
    }

    hipLaunchKernelGGL(stats_final, dim3(NF / 256), dim3(256), 0, stream,
                       dsum, dsqs, duty, kp,
                       mean64, rstd64, boost64, mean32, rstd32, boost32);
    hipLaunchKernelGGL(topk_kernel, dim3(BATCH), dim3(256), 0, stream,
                       mean32, rstd32, boost32, mean64, rstd64, boost64, kp,
                       x, W, wmask, b, out);
}